// Round 5
// baseline (988.805 us; speedup 1.0000x reference)
//
#include <hip/hip_runtime.h>
#include <math.h>

constexpr int      kLevels = 16;
constexpr unsigned kT      = 1u << 19;
constexpr int      kHidden = 64;
constexpr int      kInDim  = 32;
constexpr int      kOutDim = 16;

struct LevelParams {
    float    scale[kLevels];
    unsigned res[kLevels];
    unsigned dense[kLevels];
};

typedef __attribute__((ext_vector_type(8))) short bf16x8;
typedef __attribute__((ext_vector_type(4))) float f32x4;
typedef __attribute__((ext_vector_type(2))) unsigned uint2v;

// ---- manual bf16 helpers ----
__device__ inline float bf2f(unsigned short b) {
    unsigned u = ((unsigned)b) << 16;
    return __builtin_bit_cast(float, u);
}
__device__ inline unsigned short f2bf(float f) {
    unsigned u = __builtin_bit_cast(unsigned, f);
    unsigned r = (u + 0x7fffu + ((u >> 16) & 1u)) >> 16;   // RTN-even
    return (unsigned short)r;
}
__device__ inline unsigned pack2bf(float a, float b) {
    return (unsigned)f2bf(a) | ((unsigned)f2bf(b) << 16);
}

// ---- kernel T: f32 table -> packed bf16 table in ws ----
__global__ __launch_bounds__(256) void convert_table(
        const float* __restrict__ t, unsigned* __restrict__ o, int n4)
{
    int i = blockIdx.x * blockDim.x + threadIdx.x;
    if (i >= n4) return;
    float4 v = ((const float4*)t)[i];
    ((uint2*)o)[i] = make_uint2(pack2bf(v.x, v.y), pack2bf(v.z, v.w));
}

// ---- kernel A: level-major encode, 2 points/thread, pair-merged gathers ----
__global__ __launch_bounds__(256) void encode_level(
        const float* __restrict__ x,
        const unsigned* __restrict__ tblAll,   // [16][kT] packed bf16x2
        unsigned* __restrict__ enc,            // [16][N]  packed bf16x2
        int N, LevelParams lp)
{
    const int l   = blockIdx.y;
    const int tid = threadIdx.x;
    const int pA  = blockIdx.x * 512 + tid;

    const float    scale = lp.scale[l];
    const unsigned res   = lp.res[l];
    const bool     dense = (lp.dense[l] != 0);   // wave-uniform
    const unsigned* tbl  = tblAll + (size_t)l * kT;

    #pragma unroll
    for (int half = 0; half < 2; ++half) {
        const int p = pA + half * 256;
        if (p >= N) continue;

        const float x0 = fminf(fmaxf((x[3 * p + 0] + 1.0f) * 0.5f, 0.0f), 1.0f);
        const float y0 = fminf(fmaxf((x[3 * p + 1] + 1.0f) * 0.5f, 0.0f), 1.0f);
        const float z0 = fminf(fmaxf((x[3 * p + 2] + 1.0f) * 0.5f, 0.0f), 1.0f);

        const float posx = x0 * scale + 0.5f;
        const float posy = y0 * scale + 0.5f;
        const float posz = z0 * scale + 0.5f;
        const float fgx = floorf(posx), fgy = floorf(posy), fgz = floorf(posz);
        const float fx = posx - fgx, fy = posy - fgy, fz = posz - fgz;
        const float gx = 1.0f - fx,  gy = 1.0f - fy,  gz = 1.0f - fz;
        const unsigned ix = (unsigned)fgx, iy = (unsigned)fgy, iz = (unsigned)fgz;

        // 4 (cy,cz) combos; x-corner pair merged into one 8B load where legal.
        unsigned v0[4], v1[4];   // corner values: cx=ix, cx=ix+1
        float    wyz[4];

        #pragma unroll
        for (int c2 = 0; c2 < 4; ++c2) {
            const unsigned cy = iy + (c2 & 1);
            const unsigned cz = iz + (c2 >> 1);
            wyz[c2] = ((c2 & 1) ? fy : gy) * ((c2 >> 1) ? fz : gz);

            if (dense) {
                const unsigned base = cy * res + cz * res * res;
                const unsigned idx0 = (ix + base) & (kT - 1u);
                // idx1 = idx0 + 1 (mask is a no-op for dense levels)
                if ((idx0 & 1u) == 0u) {
                    const uint2v pr = *(const uint2v*)(tbl + idx0);
                    v0[c2] = pr.x; v1[c2] = pr.y;
                } else {
                    v0[c2] = tbl[idx0];
                    v1[c2] = tbl[idx0 + 1u];
                }
            } else {
                const unsigned base = (cy * 2654435761u) ^ (cz * 805459861u);
                const unsigned idx0 = (ix ^ base) & (kT - 1u);
                if ((ix & 1u) == 0u) {
                    // idx1 = idx0 ^ 1 -> aligned pair covers both corners
                    const unsigned b = idx0 & ~1u;
                    const uint2v pr =
                        __builtin_nontemporal_load((const uint2v*)(tbl + b));
                    const bool sw = (idx0 & 1u) != 0u;
                    v0[c2] = sw ? pr.y : pr.x;
                    v1[c2] = sw ? pr.x : pr.y;
                } else {
                    const unsigned idx1 = ((ix + 1u) ^ base) & (kT - 1u);
                    v0[c2] = __builtin_nontemporal_load(tbl + idx0);
                    v1[c2] = __builtin_nontemporal_load(tbl + idx1);
                }
            }
        }

        float a0 = 0.0f, a1 = 0.0f;
        #pragma unroll
        for (int c2 = 0; c2 < 4; ++c2) {
            const float w0 = gx * wyz[c2];
            const float w1 = fx * wyz[c2];
            a0 = fmaf(bf2f((unsigned short)(v0[c2] & 0xffffu)), w0, a0);
            a1 = fmaf(bf2f((unsigned short)(v0[c2] >> 16)),     w0, a1);
            a0 = fmaf(bf2f((unsigned short)(v1[c2] & 0xffffu)), w1, a0);
            a1 = fmaf(bf2f((unsigned short)(v1[c2] >> 16)),     w1, a1);
        }
        enc[(size_t)l * N + p] = pack2bf(a0, a1);
    }
}

// ---- kernel B: MFMA MLP over bf16 enc ----
__global__ __launch_bounds__(256) void mlp_mfma(
        const unsigned* __restrict__ enc,      // [16][N] packed bf16x2
        const float* __restrict__ W0,
        const float* __restrict__ b0,
        const float* __restrict__ W1,
        const float* __restrict__ b1,
        float* __restrict__ out, int N, int nTiles)
{
    constexpr int kHStride = 72;
    __shared__ short lds_h[4][16 * kHStride];

    const int wave = threadIdx.x >> 6;
    const int lane = threadIdx.x & 63;
    const int quad = lane >> 4;
    const int l16  = lane & 15;

    union Frag { bf16x8 v; short s[8]; unsigned u[4]; };

    Frag w0f[4];
    #pragma unroll
    for (int hb = 0; hb < 4; ++hb) {
        #pragma unroll
        for (int j = 0; j < 8; ++j) {
            const int k = quad * 8 + j;
            const int n = hb * 16 + l16;
            w0f[hb].s[j] = (short)f2bf(W0[n * kInDim + k]);
        }
    }
    Frag w1f[2];
    #pragma unroll
    for (int kb = 0; kb < 2; ++kb) {
        #pragma unroll
        for (int j = 0; j < 8; ++j) {
            const int k = kb * 32 + quad * 8 + j;
            const int n = l16;
            w1f[kb].s[j] = (short)f2bf(W1[n * kHidden + k]);
        }
    }
    float b0v[4];
    #pragma unroll
    for (int hb = 0; hb < 4; ++hb) b0v[hb] = b0[hb * 16 + l16];
    const float b1v = b1[l16];

    short* hrow = lds_h[wave];
    const int waveGlobal = blockIdx.x * 4 + wave;
    const int nWaves     = gridDim.x * 4;

    for (int t = waveGlobal; t < nTiles; t += nWaves) {
        const int P = t * 16;
        int p = P + l16;
        if (p >= N) p = N - 1;

        Frag af;
        #pragma unroll
        for (int j2 = 0; j2 < 4; ++j2)
            af.u[j2] = enc[(size_t)(quad * 4 + j2) * N + p];

        f32x4 acc[4];
        #pragma unroll
        for (int hb = 0; hb < 4; ++hb) {
            acc[hb] = f32x4{b0v[hb], b0v[hb], b0v[hb], b0v[hb]};
            acc[hb] = __builtin_amdgcn_mfma_f32_16x16x32_bf16(
                          af.v, w0f[hb].v, acc[hb], 0, 0, 0);
        }

        #pragma unroll
        for (int hb = 0; hb < 4; ++hb) {
            #pragma unroll
            for (int r = 0; r < 4; ++r) {
                const float a = acc[hb][r];
                const float z = 100.0f * a;
                const float h = (z > 20.0f) ? a
                              : (__logf(1.0f + __expf(z)) * 0.01f);
                const int row = quad * 4 + r;
                const int col = hb * 16 + l16;
                hrow[row * kHStride + col] = (short)f2bf(h);
            }
        }
        bf16x8 h0 = *(const bf16x8*)&hrow[l16 * kHStride + quad * 8];
        bf16x8 h1 = *(const bf16x8*)&hrow[l16 * kHStride + 32 + quad * 8];

        f32x4 acc2 = f32x4{b1v, b1v, b1v, b1v};
        acc2 = __builtin_amdgcn_mfma_f32_16x16x32_bf16(h0, w1f[0].v, acc2, 0, 0, 0);
        acc2 = __builtin_amdgcn_mfma_f32_16x16x32_bf16(h1, w1f[1].v, acc2, 0, 0, 0);

        #pragma unroll
        for (int r = 0; r < 4; ++r) {
            const int pp = P + quad * 4 + r;
            if (pp < N) {
                if (l16 == 0) out[pp] = acc2[r];
                else out[(size_t)N + (size_t)pp * 15u + (l16 - 1)] = acc2[r];
            }
        }
    }
}

// ---- fallback: fused kernel (used only if ws too small) ----
__global__ __launch_bounds__(256) void sdf_fused(
        const float* __restrict__ x, const float* __restrict__ table,
        const float* __restrict__ W0, const float* __restrict__ b0,
        const float* __restrict__ W1, const float* __restrict__ b1,
        float* __restrict__ out, int N, LevelParams lp)
{
    const int gid = blockIdx.x * blockDim.x + threadIdx.x;
    if (gid >= N) return;
    const float x0 = fminf(fmaxf((x[3 * gid + 0] + 1.0f) * 0.5f, 0.0f), 1.0f);
    const float y0 = fminf(fmaxf((x[3 * gid + 1] + 1.0f) * 0.5f, 0.0f), 1.0f);
    const float z0 = fminf(fmaxf((x[3 * gid + 2] + 1.0f) * 0.5f, 0.0f), 1.0f);
    float enc[kInDim];
    #pragma unroll
    for (int l = 0; l < kLevels; ++l) {
        const float scale = lp.scale[l];
        const unsigned res = lp.res[l];
        const bool dense = (lp.dense[l] != 0);
        const float posx = x0 * scale + 0.5f, posy = y0 * scale + 0.5f, posz = z0 * scale + 0.5f;
        const float fgx = floorf(posx), fgy = floorf(posy), fgz = floorf(posz);
        const float fx = posx - fgx, fy = posy - fgy, fz = posz - fgz;
        const float gx = 1.0f - fx, gy = 1.0f - fy, gz = 1.0f - fz;
        const unsigned ix = (unsigned)fgx, iy = (unsigned)fgy, iz = (unsigned)fgz;
        const float* tbl = table + (size_t)l * kT * 2u;
        float a0 = 0.0f, a1 = 0.0f;
        #pragma unroll
        for (int c = 0; c < 8; ++c) {
            const unsigned cx = ix + (c & 1), cy = iy + ((c >> 1) & 1), cz = iz + ((c >> 2) & 1);
            unsigned idx = dense ? (cx + cy * res + cz * res * res)
                                 : (cx ^ (cy * 2654435761u) ^ (cz * 805459861u));
            idx &= (kT - 1u);
            const float2 tv = *(const float2*)(tbl + 2u * idx);
            const float w = ((c & 1) ? fx : gx) * (((c >> 1) & 1) ? fy : gy) * (((c >> 2) & 1) ? fz : gz);
            a0 = fmaf(tv.x, w, a0); a1 = fmaf(tv.y, w, a1);
        }
        enc[2 * l] = a0; enc[2 * l + 1] = a1;
    }
    float acc[kOutDim];
    #pragma unroll
    for (int k = 0; k < kOutDim; ++k) acc[k] = b1[k];
    #pragma unroll 2
    for (int j = 0; j < kHidden; ++j) {
        float a = b0[j];
        #pragma unroll
        for (int i = 0; i < kInDim; ++i) a = fmaf(enc[i], W0[j * kInDim + i], a);
        const float z = 100.0f * a;
        const float h = (z > 20.0f) ? a : (__logf(1.0f + __expf(z)) * 0.01f);
        #pragma unroll
        for (int k = 0; k < kOutDim; ++k) acc[k] = fmaf(h, W1[k * kHidden + j], acc[k]);
    }
    out[gid] = acc[0];
    #pragma unroll
    for (int k = 0; k < 15; ++k) out[(size_t)N + (size_t)gid * 15u + k] = acc[k + 1];
}

extern "C" void kernel_launch(void* const* d_in, const int* in_sizes, int n_in,
                              void* d_out, int out_size, void* d_ws, size_t ws_size,
                              hipStream_t stream) {
    const float* x     = (const float*)d_in[0];
    const float* table = (const float*)d_in[1];
    const float* W0    = (const float*)d_in[2];
    const float* b0    = (const float*)d_in[3];
    const float* W1    = (const float*)d_in[4];
    const float* b1    = (const float*)d_in[5];
    float* out = (float*)d_out;
    const int N = in_sizes[0] / 3;

    LevelParams lp;
    const double s = exp2(7.0 / 15.0);
    for (int l = 0; l < kLevels; ++l) {
        const double sc = 16.0 * pow(s, (double)l) - 1.0;
        lp.scale[l] = (float)sc;
        const unsigned res = (unsigned)ceil(sc) + 1u;
        lp.res[l] = res;
        lp.dense[l] =
            ((unsigned long long)res * res * res <= (unsigned long long)kT) ? 1u : 0u;
    }

    const size_t tbl_bytes = (size_t)kLevels * kT * 4u;              // 32 MB packed bf16x2
    const size_t enc_bytes = (size_t)kLevels * (size_t)N * 4u;       // 64 MB packed bf16x2

    if (ws_size >= tbl_bytes + enc_bytes) {
        unsigned* tbl_bf = (unsigned*)d_ws;
        unsigned* enc    = (unsigned*)((char*)d_ws + tbl_bytes);

        const int n4 = (int)(kLevels * kT * 2u / 4u);
        hipLaunchKernelGGL(convert_table, dim3((n4 + 255) / 256), dim3(256), 0, stream,
                           table, tbl_bf, n4);

        dim3 gridA((N + 511) / 512, kLevels);
        hipLaunchKernelGGL(encode_level, gridA, dim3(256), 0, stream,
                           x, tbl_bf, enc, N, lp);

        const int nTiles = (N + 15) / 16;
        hipLaunchKernelGGL(mlp_mfma, dim3(2048), dim3(256), 0, stream,
                           enc, W0, b0, W1, b1, out, N, nTiles);
    } else {
        hipLaunchKernelGGL(sdf_fused, dim3((N + 255) / 256), dim3(256), 0, stream,
                           x, table, W0, b0, W1, b1, out, N, lp);
    }
}

// Round 6
// 448.764 us; speedup vs baseline: 2.2034x; 2.2034x over previous
//
#include <hip/hip_runtime.h>
#include <math.h>

constexpr int      kLevels = 16;
constexpr unsigned kT      = 1u << 19;
constexpr int      kHidden = 64;
constexpr int      kInDim  = 32;
constexpr int      kOutDim = 16;

struct LevelParams {
    float    scale[kLevels];
    unsigned res[kLevels];
    unsigned dense[kLevels];
};

typedef __attribute__((ext_vector_type(8))) short bf16x8;
typedef __attribute__((ext_vector_type(4))) float f32x4;
typedef __attribute__((ext_vector_type(2))) unsigned uint2v;

// ---- manual bf16 helpers ----
__device__ inline float bf2f(unsigned short b) {
    unsigned u = ((unsigned)b) << 16;
    return __builtin_bit_cast(float, u);
}
__device__ inline unsigned short f2bf(float f) {
    unsigned u = __builtin_bit_cast(unsigned, f);
    unsigned r = (u + 0x7fffu + ((u >> 16) & 1u)) >> 16;   // RTN-even
    return (unsigned short)r;
}
__device__ inline unsigned pack2bf(float a, float b) {
    return (unsigned)f2bf(a) | ((unsigned)f2bf(b) << 16);
}

// ---- kernel T: f32 table -> packed bf16 table in ws ----
__global__ __launch_bounds__(256) void convert_table(
        const float* __restrict__ t, unsigned* __restrict__ o, int n4)
{
    int i = blockIdx.x * blockDim.x + threadIdx.x;
    if (i >= n4) return;
    float4 v = ((const float4*)t)[i];
    ((uint2*)o)[i] = make_uint2(pack2bf(v.x, v.y), pack2bf(v.z, v.w));
}

// ---- kernel A: level-major encode, 2 points/thread, pair-merged gathers.
// NOTE: no nontemporal loads — nt defeats L2 allocation on gfx950
// (R4: FETCH_SIZE 162MB -> 1.57GB, encode 394 -> 814 us). Table gathers
// MUST stay L2-cacheable.
__global__ __launch_bounds__(256) void encode_level(
        const float* __restrict__ x,
        const unsigned* __restrict__ tblAll,   // [16][kT] packed bf16x2
        unsigned* __restrict__ enc,            // [16][N]  packed bf16x2
        int N, LevelParams lp)
{
    const int l   = blockIdx.y;
    const int tid = threadIdx.x;
    const int pA  = blockIdx.x * 512 + tid;

    const float    scale = lp.scale[l];
    const unsigned res   = lp.res[l];
    const bool     dense = (lp.dense[l] != 0);   // wave-uniform
    const unsigned* tbl  = tblAll + (size_t)l * kT;

    #pragma unroll
    for (int half = 0; half < 2; ++half) {
        const int p = pA + half * 256;
        if (p >= N) continue;

        const float x0 = fminf(fmaxf((x[3 * p + 0] + 1.0f) * 0.5f, 0.0f), 1.0f);
        const float y0 = fminf(fmaxf((x[3 * p + 1] + 1.0f) * 0.5f, 0.0f), 1.0f);
        const float z0 = fminf(fmaxf((x[3 * p + 2] + 1.0f) * 0.5f, 0.0f), 1.0f);

        const float posx = x0 * scale + 0.5f;
        const float posy = y0 * scale + 0.5f;
        const float posz = z0 * scale + 0.5f;
        const float fgx = floorf(posx), fgy = floorf(posy), fgz = floorf(posz);
        const float fx = posx - fgx, fy = posy - fgy, fz = posz - fgz;
        const float gx = 1.0f - fx,  gy = 1.0f - fy,  gz = 1.0f - fz;
        const unsigned ix = (unsigned)fgx, iy = (unsigned)fgy, iz = (unsigned)fgz;

        // 4 (cy,cz) combos; x-corner pair merged into one 8B load where legal.
        unsigned v0[4], v1[4];   // corner values: cx=ix, cx=ix+1
        float    wyz[4];

        #pragma unroll
        for (int c2 = 0; c2 < 4; ++c2) {
            const unsigned cy = iy + (c2 & 1);
            const unsigned cz = iz + (c2 >> 1);
            wyz[c2] = ((c2 & 1) ? fy : gy) * ((c2 >> 1) ? fz : gz);

            if (dense) {
                const unsigned base = cy * res + cz * res * res;
                const unsigned idx0 = (ix + base) & (kT - 1u);
                // idx1 = idx0 + 1 (mask is a no-op for dense levels)
                if ((idx0 & 1u) == 0u) {
                    const uint2v pr = *(const uint2v*)(tbl + idx0);
                    v0[c2] = pr.x; v1[c2] = pr.y;
                } else {
                    v0[c2] = tbl[idx0];
                    v1[c2] = tbl[idx0 + 1u];
                }
            } else {
                const unsigned base = (cy * 2654435761u) ^ (cz * 805459861u);
                const unsigned idx0 = (ix ^ base) & (kT - 1u);
                if ((ix & 1u) == 0u) {
                    // ix even -> idx1 = idx0 ^ 1: aligned pair covers both
                    const unsigned b = idx0 & ~1u;
                    const uint2v pr = *(const uint2v*)(tbl + b);
                    const bool sw = (idx0 & 1u) != 0u;
                    v0[c2] = sw ? pr.y : pr.x;
                    v1[c2] = sw ? pr.x : pr.y;
                } else {
                    const unsigned idx1 = ((ix + 1u) ^ base) & (kT - 1u);
                    v0[c2] = tbl[idx0];
                    v1[c2] = tbl[idx1];
                }
            }
        }

        float a0 = 0.0f, a1 = 0.0f;
        #pragma unroll
        for (int c2 = 0; c2 < 4; ++c2) {
            const float w0 = gx * wyz[c2];
            const float w1 = fx * wyz[c2];
            a0 = fmaf(bf2f((unsigned short)(v0[c2] & 0xffffu)), w0, a0);
            a1 = fmaf(bf2f((unsigned short)(v0[c2] >> 16)),     w0, a1);
            a0 = fmaf(bf2f((unsigned short)(v1[c2] & 0xffffu)), w1, a0);
            a1 = fmaf(bf2f((unsigned short)(v1[c2] >> 16)),     w1, a1);
        }
        enc[(size_t)l * N + p] = pack2bf(a0, a1);
    }
}

// ---- kernel B: MFMA MLP over bf16 enc ----
__global__ __launch_bounds__(256) void mlp_mfma(
        const unsigned* __restrict__ enc,      // [16][N] packed bf16x2
        const float* __restrict__ W0,
        const float* __restrict__ b0,
        const float* __restrict__ W1,
        const float* __restrict__ b1,
        float* __restrict__ out, int N, int nTiles)
{
    constexpr int kHStride = 72;
    __shared__ short lds_h[4][16 * kHStride];

    const int wave = threadIdx.x >> 6;
    const int lane = threadIdx.x & 63;
    const int quad = lane >> 4;
    const int l16  = lane & 15;

    union Frag { bf16x8 v; short s[8]; unsigned u[4]; };

    Frag w0f[4];
    #pragma unroll
    for (int hb = 0; hb < 4; ++hb) {
        #pragma unroll
        for (int j = 0; j < 8; ++j) {
            const int k = quad * 8 + j;
            const int n = hb * 16 + l16;
            w0f[hb].s[j] = (short)f2bf(W0[n * kInDim + k]);
        }
    }
    Frag w1f[2];
    #pragma unroll
    for (int kb = 0; kb < 2; ++kb) {
        #pragma unroll
        for (int j = 0; j < 8; ++j) {
            const int k = kb * 32 + quad * 8 + j;
            const int n = l16;
            w1f[kb].s[j] = (short)f2bf(W1[n * kHidden + k]);
        }
    }
    float b0v[4];
    #pragma unroll
    for (int hb = 0; hb < 4; ++hb) b0v[hb] = b0[hb * 16 + l16];
    const float b1v = b1[l16];

    short* hrow = lds_h[wave];
    const int waveGlobal = blockIdx.x * 4 + wave;
    const int nWaves     = gridDim.x * 4;

    for (int t = waveGlobal; t < nTiles; t += nWaves) {
        const int P = t * 16;
        int p = P + l16;
        if (p >= N) p = N - 1;

        Frag af;
        #pragma unroll
        for (int j2 = 0; j2 < 4; ++j2)
            af.u[j2] = enc[(size_t)(quad * 4 + j2) * N + p];

        f32x4 acc[4];
        #pragma unroll
        for (int hb = 0; hb < 4; ++hb) {
            acc[hb] = f32x4{b0v[hb], b0v[hb], b0v[hb], b0v[hb]};
            acc[hb] = __builtin_amdgcn_mfma_f32_16x16x32_bf16(
                          af.v, w0f[hb].v, acc[hb], 0, 0, 0);
        }

        #pragma unroll
        for (int hb = 0; hb < 4; ++hb) {
            #pragma unroll
            for (int r = 0; r < 4; ++r) {
                const float a = acc[hb][r];
                const float z = 100.0f * a;
                const float h = (z > 20.0f) ? a
                              : (__logf(1.0f + __expf(z)) * 0.01f);
                const int row = quad * 4 + r;
                const int col = hb * 16 + l16;
                hrow[row * kHStride + col] = (short)f2bf(h);
            }
        }
        bf16x8 h0 = *(const bf16x8*)&hrow[l16 * kHStride + quad * 8];
        bf16x8 h1 = *(const bf16x8*)&hrow[l16 * kHStride + 32 + quad * 8];

        f32x4 acc2 = f32x4{b1v, b1v, b1v, b1v};
        acc2 = __builtin_amdgcn_mfma_f32_16x16x32_bf16(h0, w1f[0].v, acc2, 0, 0, 0);
        acc2 = __builtin_amdgcn_mfma_f32_16x16x32_bf16(h1, w1f[1].v, acc2, 0, 0, 0);

        #pragma unroll
        for (int r = 0; r < 4; ++r) {
            const int pp = P + quad * 4 + r;
            if (pp < N) {
                if (l16 == 0) out[pp] = acc2[r];
                else out[(size_t)N + (size_t)pp * 15u + (l16 - 1)] = acc2[r];
            }
        }
    }
}

// ---- fallback: fused kernel (used only if ws too small) ----
__global__ __launch_bounds__(256) void sdf_fused(
        const float* __restrict__ x, const float* __restrict__ table,
        const float* __restrict__ W0, const float* __restrict__ b0,
        const float* __restrict__ W1, const float* __restrict__ b1,
        float* __restrict__ out, int N, LevelParams lp)
{
    const int gid = blockIdx.x * blockDim.x + threadIdx.x;
    if (gid >= N) return;
    const float x0 = fminf(fmaxf((x[3 * gid + 0] + 1.0f) * 0.5f, 0.0f), 1.0f);
    const float y0 = fminf(fmaxf((x[3 * gid + 1] + 1.0f) * 0.5f, 0.0f), 1.0f);
    const float z0 = fminf(fmaxf((x[3 * gid + 2] + 1.0f) * 0.5f, 0.0f), 1.0f);
    float enc[kInDim];
    #pragma unroll
    for (int l = 0; l < kLevels; ++l) {
        const float scale = lp.scale[l];
        const unsigned res = lp.res[l];
        const bool dense = (lp.dense[l] != 0);
        const float posx = x0 * scale + 0.5f, posy = y0 * scale + 0.5f, posz = z0 * scale + 0.5f;
        const float fgx = floorf(posx), fgy = floorf(posy), fgz = floorf(posz);
        const float fx = posx - fgx, fy = posy - fgy, fz = posz - fgz;
        const float gx = 1.0f - fx, gy = 1.0f - fy, gz = 1.0f - fz;
        const unsigned ix = (unsigned)fgx, iy = (unsigned)fgy, iz = (unsigned)fgz;
        const float* tbl = table + (size_t)l * kT * 2u;
        float a0 = 0.0f, a1 = 0.0f;
        #pragma unroll
        for (int c = 0; c < 8; ++c) {
            const unsigned cx = ix + (c & 1), cy = iy + ((c >> 1) & 1), cz = iz + ((c >> 2) & 1);
            unsigned idx = dense ? (cx + cy * res + cz * res * res)
                                 : (cx ^ (cy * 2654435761u) ^ (cz * 805459861u));
            idx &= (kT - 1u);
            const float2 tv = *(const float2*)(tbl + 2u * idx);
            const float w = ((c & 1) ? fx : gx) * (((c >> 1) & 1) ? fy : gy) * (((c >> 2) & 1) ? fz : gz);
            a0 = fmaf(tv.x, w, a0); a1 = fmaf(tv.y, w, a1);
        }
        enc[2 * l] = a0; enc[2 * l + 1] = a1;
    }
    float acc[kOutDim];
    #pragma unroll
    for (int k = 0; k < kOutDim; ++k) acc[k] = b1[k];
    #pragma unroll 2
    for (int j = 0; j < kHidden; ++j) {
        float a = b0[j];
        #pragma unroll
        for (int i = 0; i < kInDim; ++i) a = fmaf(enc[i], W0[j * kInDim + i], a);
        const float z = 100.0f * a;
        const float h = (z > 20.0f) ? a : (__logf(1.0f + __expf(z)) * 0.01f);
        #pragma unroll
        for (int k = 0; k < kOutDim; ++k) acc[k] = fmaf(h, W1[k * kHidden + j], acc[k]);
    }
    out[gid] = acc[0];
    #pragma unroll
    for (int k = 0; k < 15; ++k) out[(size_t)N + (size_t)gid * 15u + k] = acc[k + 1];
}

extern "C" void kernel_launch(void* const* d_in, const int* in_sizes, int n_in,
                              void* d_out, int out_size, void* d_ws, size_t ws_size,
                              hipStream_t stream) {
    const float* x     = (const float*)d_in[0];
    const float* table = (const float*)d_in[1];
    const float* W0    = (const float*)d_in[2];
    const float* b0    = (const float*)d_in[3];
    const float* W1    = (const float*)d_in[4];
    const float* b1    = (const float*)d_in[5];
    float* out = (float*)d_out;
    const int N = in_sizes[0] / 3;

    LevelParams lp;
    const double s = exp2(7.0 / 15.0);
    for (int l = 0; l < kLevels; ++l) {
        const double sc = 16.0 * pow(s, (double)l) - 1.0;
        lp.scale[l] = (float)sc;
        const unsigned res = (unsigned)ceil(sc) + 1u;
        lp.res[l] = res;
        lp.dense[l] =
            ((unsigned long long)res * res * res <= (unsigned long long)kT) ? 1u : 0u;
    }

    const size_t tbl_bytes = (size_t)kLevels * kT * 4u;              // 32 MB packed bf16x2
    const size_t enc_bytes = (size_t)kLevels * (size_t)N * 4u;       // 64 MB packed bf16x2

    if (ws_size >= tbl_bytes + enc_bytes) {
        unsigned* tbl_bf = (unsigned*)d_ws;
        unsigned* enc    = (unsigned*)((char*)d_ws + tbl_bytes);

        const int n4 = (int)(kLevels * kT * 2u / 4u);
        hipLaunchKernelGGL(convert_table, dim3((n4 + 255) / 256), dim3(256), 0, stream,
                           table, tbl_bf, n4);

        dim3 gridA((N + 511) / 512, kLevels);
        hipLaunchKernelGGL(encode_level, gridA, dim3(256), 0, stream,
                           x, tbl_bf, enc, N, lp);

        const int nTiles = (N + 15) / 16;
        hipLaunchKernelGGL(mlp_mfma, dim3(2048), dim3(256), 0, stream,
                           enc, W0, b0, W1, b1, out, N, nTiles);
    } else {
        hipLaunchKernelGGL(sdf_fused, dim3((N + 255) / 256), dim3(256), 0, stream,
                           x, table, W0, b0, W1, b1, out, N, lp);
    }
}